// Round 6
// baseline (1505.332 us; speedup 1.0000x reference)
//
#include <hip/hip_runtime.h>
#include <math.h>

// ---------------- constants ----------------
#define NTOK   1568
#define BATCH  2
#define HID    1024
#define MLPD   4096
#define NLAYER 4
#define ROWS   (BATCH*NTOK)   // 3136
#define CONVK  1536

typedef __bf16 bf16x8 __attribute__((ext_vector_type(8)));
typedef float  f32x4  __attribute__((ext_vector_type(4)));

__device__ __forceinline__ unsigned short f2b(float f) {
  unsigned int u = __float_as_uint(f);
  unsigned int r = u + 0x7FFFu + ((u >> 16) & 1u);   // RNE
  return (unsigned short)(r >> 16);
}
__device__ __forceinline__ float b2f(unsigned short s) {
  return __uint_as_float((unsigned int)s << 16);
}

// async global->LDS 16B; lds ptr must be wave-uniform base (HW adds lane*16)
__device__ __forceinline__ void async16(const unsigned short* g, unsigned short* l) {
  __builtin_amdgcn_global_load_lds(
      (__attribute__((address_space(1))) void*)(void*)g,
      (__attribute__((address_space(3))) void*)(void*)l, 16, 0, 0);
}

// ---------------- fp32 -> bf16 cast (x4 vectorized, grid-stride) ----------------
__global__ __launch_bounds__(256) void cast4_k(const float* __restrict__ s,
                                               unsigned short* __restrict__ d,
                                               long long n4) {
  long long i = (long long)blockIdx.x * 256 + threadIdx.x;
  long long stride = (long long)gridDim.x * 256;
  for (; i < n4; i += stride) {
    float4 v = ((const float4*)s)[i];
    *(ushort4*)(d + i * 4) = make_ushort4(f2b(v.x), f2b(v.y), f2b(v.z), f2b(v.w));
  }
}

// cast q/k/v weights into one concatenated per-layer buffer wQKV[L][3072][1024]
__global__ __launch_bounds__(256) void castqkv_k(const float* __restrict__ q,
                                                 const float* __restrict__ k,
                                                 const float* __restrict__ v,
                                                 unsigned short* __restrict__ dst) {
  const float* src = blockIdx.y == 0 ? q : (blockIdx.y == 1 ? k : v);
  long long i4 = (long long)blockIdx.x * 256 + threadIdx.x;   // exactly L*HH/4
  long long e = i4 * 4;
  int layer = (int)(e >> 20);                                  // HH = 1<<20
  long long de = e + ((long long)(2 * layer + blockIdx.y) << 20);
  float4 val = ((const float4*)src)[i4];
  *(ushort4*)(dst + de) = make_ushort4(f2b(val.x), f2b(val.y), f2b(val.z), f2b(val.w));
}

__global__ __launch_bounds__(256) void biascat_k(const float* __restrict__ qb,
                                                 const float* __restrict__ kb,
                                                 const float* __restrict__ vb,
                                                 float* __restrict__ dst) {
  int idx = blockIdx.x * 256 + threadIdx.x;   // L*3072
  int layer = idx / 3072, c = idx % 3072;
  float v = c < 1024 ? qb[layer * 1024 + c]
            : (c < 2048 ? kb[layer * 1024 + c - 1024] : vb[layer * 1024 + c - 2048]);
  dst[idx] = v;
}

// ---------------- im2col for the tubelet conv ----------------
__global__ __launch_bounds__(256) void im2col_k(const float* __restrict__ pv,
                                                unsigned short* __restrict__ A) {
  int idx = blockIdx.x * 256 + threadIdx.x;       // exactly ROWS*CONVK threads
  int row = idx / CONVK, col = idx % CONVK;
  int b = row / NTOK, t = row % NTOK;
  int d = t / 196, r = t % 196, hh = r / 14, ww = r % 14;
  int c = col >> 9, r2 = col & 511, td = r2 >> 8, ph = (r2 >> 4) & 15, pw = r2 & 15;
  int frame = 2 * d + td;
  const float* src = pv + ((((long long)b * 16 + frame) * 3 + c) * 224 + (hh * 16 + ph)) * 224
                        + (ww * 16 + pw);
  A[idx] = f2b(*src);
}

// ---------------- GEMM: partial[z][M,N] = A[M,K_z](bf16) * B[N,K_z]^T(bf16) ----------
// Double-buffered LDS (flash4-style: 1 barrier/iter, stage kt+1 then compute kt).
// blockIdx.z selects K-chunk [z*kChunk,(z+1)*kChunk); writes bf16 partial per z.
__global__ __launch_bounds__(256) void gemm_bt(const unsigned short* __restrict__ A,
                                               const unsigned short* __restrict__ B,
                                               unsigned short* __restrict__ outP,
                                               int M, int N, int K, int kChunk) {
  __shared__ unsigned short As[2][128 * 32];
  __shared__ unsigned short Bs[2][128 * 32];
  const int tid = threadIdx.x;
  const int lane = tid & 63;
  const int w = tid >> 6;
  const int wm = (w >> 1) * 64, wn = (w & 1) * 64;
  const int l15 = lane & 15, l4 = lane >> 4;
  const int bm = blockIdx.y, bn = blockIdx.x;
  const int wbase = tid & ~63;   // wave-uniform
  const int kbeg = blockIdx.z * kChunk;

  auto stage = [&](int buf, int k0) {
#pragma unroll
    for (int it = 0; it < 2; ++it) {
      int c = it * 256 + tid;
      int rowA = bm * 128 + (c >> 2);
      if (rowA >= M) rowA = M - 1;
      async16(A + (size_t)rowA * K + k0 + (c & 3) * 8, &As[buf][(it * 256 + wbase) * 8]);
      int rowB = bn * 128 + (c >> 2);
      async16(B + (size_t)rowB * K + k0 + (c & 3) * 8, &Bs[buf][(it * 256 + wbase) * 8]);
    }
  };

  f32x4 acc[4][4] = {};
  stage(0, kbeg);
  const int nIter = kChunk >> 5;

  for (int i = 0; i < nIter; ++i) {
    const int cur = i & 1;
    __syncthreads();               // drains stage(cur) issued one compute-phase ago
    if (i + 1 < nIter) stage(cur ^ 1, kbeg + (i + 1) * 32);

    bf16x8 af[4], bfr[4];
#pragma unroll
    for (int ii = 0; ii < 4; ++ii)
      af[ii] = *(const bf16x8*)&As[cur][(wm + ii * 16 + l15) * 32 + l4 * 8];
#pragma unroll
    for (int j = 0; j < 4; ++j)
      bfr[j] = *(const bf16x8*)&Bs[cur][(wn + j * 16 + l15) * 32 + l4 * 8];
#pragma unroll
    for (int ii = 0; ii < 4; ++ii)
#pragma unroll
      for (int j = 0; j < 4; ++j)
        acc[ii][j] = __builtin_amdgcn_mfma_f32_16x16x32_bf16(af[ii], bfr[j], acc[ii][j], 0, 0, 0);
  }

  unsigned short* pout = outP + (size_t)blockIdx.z * ((size_t)M * N);
#pragma unroll
  for (int ii = 0; ii < 4; ++ii) {
    int rowb = bm * 128 + wm + ii * 16 + l4 * 4;
#pragma unroll
    for (int r = 0; r < 4; ++r) {
      int rr = rowb + r;
      if (rr >= M) continue;
#pragma unroll
      for (int j = 0; j < 4; ++j) {
        int col = bn * 128 + wn + j * 16 + l15;
        pout[(size_t)rr * N + col] = f2b(acc[ii][j][r]);
      }
    }
  }
}

// ---------------- split-K reduce: sum NP bf16 partials + bias (+resid/gelu) ----------
template <int NP, int RESID, int GELU, int OUTB>
__global__ __launch_bounds__(256) void reduceN_k(const unsigned short* __restrict__ p,
                                                 const float* __restrict__ bias,
                                                 const float* __restrict__ resid,
                                                 float* __restrict__ outF,
                                                 unsigned short* __restrict__ outB,
                                                 int MN, int N) {
  int i8 = blockIdx.x * 256 + threadIdx.x;   // exactly MN/8 threads
  int e = i8 * 8;
  float acc[8];
#pragma unroll
  for (int j = 0; j < 8; ++j) acc[j] = 0.0f;
#pragma unroll
  for (int pp = 0; pp < NP; ++pp) {
    const unsigned short* src = p + (size_t)pp * MN + e;
    ushort4 a0 = *(const ushort4*)src;
    ushort4 a1 = *(const ushort4*)(src + 4);
    acc[0] += b2f(a0.x); acc[1] += b2f(a0.y); acc[2] += b2f(a0.z); acc[3] += b2f(a0.w);
    acc[4] += b2f(a1.x); acc[5] += b2f(a1.y); acc[6] += b2f(a1.z); acc[7] += b2f(a1.w);
  }
  int col = e % N;                           // N % 8 == 0, so 8 elems stay in-row
  float4 b0 = *(const float4*)(bias + col);
  float4 b1 = *(const float4*)(bias + col + 4);
  acc[0] += b0.x; acc[1] += b0.y; acc[2] += b0.z; acc[3] += b0.w;
  acc[4] += b1.x; acc[5] += b1.y; acc[6] += b1.z; acc[7] += b1.w;
  if (RESID) {
    float4 r0 = *(const float4*)(resid + e);
    float4 r1 = *(const float4*)(resid + e + 4);
    acc[0] += r0.x; acc[1] += r0.y; acc[2] += r0.z; acc[3] += r0.w;
    acc[4] += r1.x; acc[5] += r1.y; acc[6] += r1.z; acc[7] += r1.w;
  }
  if (GELU) {
#pragma unroll
    for (int j = 0; j < 8; ++j)
      acc[j] = 0.5f * acc[j] * (1.0f + erff(acc[j] * 0.70710678118654752f));
  }
  if (OUTB) {
    *(ushort4*)(outB + e) = make_ushort4(f2b(acc[0]), f2b(acc[1]), f2b(acc[2]), f2b(acc[3]));
    *(ushort4*)(outB + e + 4) = make_ushort4(f2b(acc[4]), f2b(acc[5]), f2b(acc[6]), f2b(acc[7]));
  } else {
    *(float4*)(outF + e) = make_float4(acc[0], acc[1], acc[2], acc[3]);
    *(float4*)(outF + e + 4) = make_float4(acc[4], acc[5], acc[6], acc[7]);
  }
}

// ---------------- LayerNorm (row=1024) ----------------
template <int OUT_BF16>
__global__ __launch_bounds__(256) void ln_k(const float* __restrict__ x,
                                            const float* __restrict__ g,
                                            const float* __restrict__ b,
                                            unsigned short* __restrict__ oB,
                                            float* __restrict__ oF) {
  __shared__ float red[8];
  const int row = blockIdx.x, tid = threadIdx.x;
  const float4 v = ((const float4*)(x + (size_t)row * HID))[tid];
  float s = v.x + v.y + v.z + v.w;
  float q = v.x * v.x + v.y * v.y + v.z * v.z + v.w * v.w;
  for (int off = 32; off; off >>= 1) { s += __shfl_xor(s, off); q += __shfl_xor(q, off); }
  if ((tid & 63) == 0) { red[tid >> 6] = s; red[4 + (tid >> 6)] = q; }
  __syncthreads();
  float ts = red[0] + red[1] + red[2] + red[3];
  float tq = red[4] + red[5] + red[6] + red[7];
  float mu = ts * (1.0f / HID);
  float var = tq * (1.0f / HID) - mu * mu;
  float rs = rsqrtf(var + 1e-6f);
  int col = tid * 4;
  float o0 = (v.x - mu) * rs * g[col + 0] + b[col + 0];
  float o1 = (v.y - mu) * rs * g[col + 1] + b[col + 1];
  float o2 = (v.z - mu) * rs * g[col + 2] + b[col + 2];
  float o3 = (v.w - mu) * rs * g[col + 3] + b[col + 3];
  if (OUT_BF16) {
    *(ushort4*)(oB + (size_t)row * HID + col) = make_ushort4(f2b(o0), f2b(o1), f2b(o2), f2b(o3));
  } else {
    *(float4*)(oF + (size_t)row * HID + col) = make_float4(o0, o1, o2, o3);
  }
}

// ---------------- QKV prep: RoPE(q,k)+scale -> head-major; V -> per-head transposed ----
// grid (25 token-tiles, 32 bh); block 256
__global__ __launch_bounds__(256) void qkvprep_k(const unsigned short* __restrict__ qkvb,
                                                 unsigned short* __restrict__ Qh,
                                                 unsigned short* __restrict__ Kh,
                                                 unsigned short* __restrict__ VT) {
  __shared__ unsigned short Vs[64 * 72];
  const int tile = blockIdx.x, bh = blockIdx.y;
  const int b = bh >> 4, head = bh & 15;
  const int tid = threadIdx.x;
  const int tl = tid >> 2, dc = tid & 3;
  const int tg = tile * 64 + tl;
  const int trc = tg < NTOK ? tg : NTOK - 1;
  const bool valid = tg < NTOK;
  const size_t srow = ((size_t)(b * NTOK + trc)) * 3072 + head * 64 + dc * 16;

  // V chunk -> LDS
  {
    uint4 v0 = *(const uint4*)(qkvb + srow + 2048);
    uint4 v1 = *(const uint4*)(qkvb + srow + 2048 + 8);
    *(uint4*)&Vs[tl * 72 + dc * 16] = v0;
    *(uint4*)&Vs[tl * 72 + dc * 16 + 8] = v1;
  }

  // RoPE on q,k (8 pairs per thread)
  const int t = trc;
  const int dpos = t / 196, rem = t - dpos * 196, hpos = rem / 14, wpos = rem - hpos * 14;
  const float LG = 0.9210340371976184f;  // ln(10000)/10
  union V16 { uint4 u[2]; unsigned short s[16]; };
  V16 qin, kin, qout, kout;
  qin.u[0] = *(const uint4*)(qkvb + srow);
  qin.u[1] = *(const uint4*)(qkvb + srow + 8);
  kin.u[0] = *(const uint4*)(qkvb + srow + 1024);
  kin.u[1] = *(const uint4*)(qkvb + srow + 1024 + 8);
#pragma unroll
  for (int p = 0; p < 8; ++p) {
    int d0 = dc * 16 + 2 * p;
    float qx0 = b2f(qin.s[2 * p]), qx1 = b2f(qin.s[2 * p + 1]);
    float kx0 = b2f(kin.s[2 * p]), kx1 = b2f(kin.s[2 * p + 1]);
    float qo0, qo1, ko0, ko1;
    if (d0 >= 60) { qo0 = qx0; qo1 = qx1; ko0 = kx0; ko1 = kx1; }
    else {
      int region = d0 / 20;
      int j0 = d0 - region * 20;
      int pos = region == 0 ? dpos : (region == 1 ? hpos : wpos);
      float fp = (float)pos;
      int i0 = j0 % 10, i1 = (j0 + 1) % 10;
      float f0 = expf(-LG * (float)i0) * fp;
      float f1 = expf(-LG * (float)i1) * fp;
      float c0 = cosf(f0), s0 = sinf(f0), c1 = cosf(f1), s1 = sinf(f1);
      qo0 = qx0 * c0 - qx1 * s0; qo1 = qx1 * c1 + qx0 * s1;
      ko0 = kx0 * c0 - kx1 * s0; ko1 = kx1 * c1 + kx0 * s1;
    }
    qout.s[2 * p]     = f2b(qo0 * 0.125f);     // fold attention scale into Q
    qout.s[2 * p + 1] = f2b(qo1 * 0.125f);
    kout.s[2 * p]     = f2b(ko0);
    kout.s[2 * p + 1] = f2b(ko1);
  }
  if (valid) {
    size_t drow = ((size_t)bh * NTOK + tg) * 64 + dc * 16;
    *(uint4*)(Qh + drow)     = qout.u[0];
    *(uint4*)(Qh + drow + 8) = qout.u[1];
    *(uint4*)(Kh + drow)     = kout.u[0];
    *(uint4*)(Kh + drow + 8) = kout.u[1];
  }
  __syncthreads();
  // V transpose out: thread = (dim, token-chunk)
  {
    int d = tid >> 2, tc = tid & 3;
    if (tile * 64 + tc * 16 < NTOK) {
      V16 o;
#pragma unroll
      for (int jj = 0; jj < 16; ++jj) o.s[jj] = Vs[(tc * 16 + jj) * 72 + d];
      unsigned short* dst = VT + ((size_t)bh * 64 + d) * NTOK + tile * 64 + tc * 16;
      *(uint4*)dst = o.u[0];
      *(uint4*)(dst + 8) = o.u[1];
    }
  }
}

// ---------------- flash attention v4: async LDS double-buffer, swizzled chunks -------
__global__ __launch_bounds__(256, 3) void flash4_k(const unsigned short* __restrict__ Qh,
                                                   const unsigned short* __restrict__ Kh,
                                                   const unsigned short* __restrict__ VT,
                                                   unsigned short* __restrict__ O) {
  __shared__ unsigned short Ks[2][64 * 64];
  __shared__ unsigned short Vs[2][64 * 64];
  __shared__ unsigned short Os[4][16 * 72];
  const int bh = blockIdx.x, qt = blockIdx.y;
  const int b = bh >> 4, head = bh & 15;
  const int tid = threadIdx.x, lane = tid & 63, w = tid >> 6;
  const int l15 = lane & 15, l4 = lane >> 4;
  const size_t hb = (size_t)bh * NTOK * 64;
  const unsigned short* kgp = Kh + hb;
  const unsigned short* vbp = VT + (size_t)bh * 64 * NTOK;

  const int srow0 = w * 8 + (lane >> 3);          // it=0 row
  const int scg0  = (lane & 7) ^ (srow0 & 7);
  const int srow1 = srow0 + 32;                   // it=1 row
  const int scg1  = (lane & 7) ^ (srow1 & 7);

  const int qrow = qt * 64 + w * 16 + l15;
  const int qrc = qrow < NTOK ? qrow : NTOK - 1;
  bf16x8 q0 = *(const bf16x8*)(Qh + hb + (size_t)qrc * 64 + l4 * 8);
  bf16x8 q1 = *(const bf16x8*)(Qh + hb + (size_t)qrc * 64 + 32 + l4 * 8);

  f32x4 oacc[4] = {};
  float m = -1e30f, l = 0.0f;

  {
    async16(kgp + (size_t)srow0 * 64 + scg0 * 8, &Ks[0][(size_t)w * 512]);
    async16(kgp + (size_t)srow1 * 64 + scg1 * 8, &Ks[0][(size_t)(w + 4) * 512]);
    async16(vbp + (size_t)srow0 * NTOK + scg0 * 8, &Vs[0][(size_t)w * 512]);
    async16(vbp + (size_t)srow1 * NTOK + scg1 * 8, &Vs[0][(size_t)(w + 4) * 512]);
  }

  const int h7 = l15 & 7;
  const int p1 = (l4 ^ h7) * 8;          // phys offset of logical chunk l4
  const int p2 = ((l4 + 4) ^ h7) * 8;    // phys offset of logical chunk l4+4

  for (int kt = 0; kt < 25; ++kt) {
    const int cur = kt & 1, nxt = cur ^ 1;
    const int kb = kt * 64;
    __syncthreads();   // vmcnt(0) drain: prefetch from last iter guaranteed landed

    if (kt < 24) {
      const int kn = kb + 64;
      async16(kgp + (size_t)(kn + srow0) * 64 + scg0 * 8, &Ks[nxt][(size_t)w * 512]);
      async16(kgp + (size_t)(kn + srow1) * 64 + scg1 * 8, &Ks[nxt][(size_t)(w + 4) * 512]);
      async16(vbp + (size_t)srow0 * NTOK + kn + scg0 * 8, &Vs[nxt][(size_t)w * 512]);
      async16(vbp + (size_t)srow1 * NTOK + kn + scg1 * 8, &Vs[nxt][(size_t)(w + 4) * 512]);
    }

    bf16x8 kc0[4], kc1[4];
#pragma unroll
    for (int nt = 0; nt < 4; ++nt) {
      const unsigned short* kr = &Ks[cur][(nt * 16 + l15) * 64];
      kc0[nt] = *(const bf16x8*)(kr + p1);
      kc1[nt] = *(const bf16x8*)(kr + p2);
    }
    f32x4 s[4] = {};
#pragma unroll
    for (int nt = 0; nt < 4; ++nt) {
      s[nt] = __builtin_amdgcn_mfma_f32_16x16x32_bf16(kc0[nt], q0, s[nt], 0, 0, 0);
      s[nt] = __builtin_amdgcn_mfma_f32_16x16x32_bf16(kc1[nt], q1, s[nt], 0, 0, 0);
    }
    bf16x8 vf0[4], vf1[4];
#pragma unroll
    for (int dt = 0; dt < 4; ++dt) {
      const unsigned short* vr = &Vs[cur][(dt * 16 + l15) * 64];
      vf0[dt] = *(const bf16x8*)(vr + p1);
      vf1[dt] = *(const bf16x8*)(vr + p2);
    }

    if (kb + 64 > NTOK) {
#pragma unroll
      for (int nt = 0; nt < 4; ++nt)
#pragma unroll
        for (int r = 0; r < 4; ++r)
          if (kb + nt * 16 + l4 * 4 + r >= NTOK) s[nt][r] = -1e30f;
    }
    float rmax = s[0][0];
#pragma unroll
    for (int nt = 0; nt < 4; ++nt)
#pragma unroll
      for (int r = 0; r < 4; ++r) rmax = fmaxf(rmax, s[nt][r]);
    rmax = fmaxf(rmax, __shfl_xor(rmax, 16));
    rmax = fmaxf(rmax, __shfl_xor(rmax, 32));
    float mn = fmaxf(m, rmax);
    float alpha = __expf(m - mn);
    m = mn;
    float rsum = 0.0f;
#pragma unroll
    for (int nt = 0; nt < 4; ++nt)
#pragma unroll
      for (int r = 0; r < 4; ++r) {
        float p = __expf(s[nt][r] - mn);
        s[nt][r] = p;
        rsum += p;
      }
    rsum += __shfl_xor(rsum, 16);
    rsum += __shfl_xor(rsum, 32);
    l = l * alpha + rsum;
#pragma unroll
    for (int dt = 0; dt < 4; ++dt)
#pragma unroll
      for (int r = 0; r < 4; ++r) oacc[dt][r] *= alpha;

    unsigned pk01[4], pk23[4];
#pragma unroll
    for (int nt = 0; nt < 4; ++nt) {
      pk01[nt] = (unsigned)f2b(s[nt][0]) | ((unsigned)f2b(s[nt][1]) << 16);
      pk23[nt] = (unsigned)f2b(s[nt][2]) | ((unsigned)f2b(s[nt][3]) << 16);
    }
    const int srcA = ((l4 & 1) << 5) | l15;
    const int srcB = srcA + 16;
    const bool hi = (l4 >> 1) != 0;
    union PB { unsigned u[4]; bf16x8 v; } pf[2];
#pragma unroll
    for (int kc = 0; kc < 2; ++kc) {
      unsigned t0, t1;
      t0 = __shfl(pk01[2 * kc], srcA); t1 = __shfl(pk01[2 * kc + 1], srcA);
      pf[kc].u[0] = hi ? t1 : t0;
      t0 = __shfl(pk23[2 * kc], srcA); t1 = __shfl(pk23[2 * kc + 1], srcA);
      pf[kc].u[1] = hi ? t1 : t0;
      t0 = __shfl(pk01[2 * kc], srcB); t1 = __shfl(pk01[2 * kc + 1], srcB);
      pf[kc].u[2] = hi ? t1 : t0;
      t0 = __shfl(pk23[2 * kc], srcB); t1 = __shfl(pk23[2 * kc + 1], srcB);
      pf[kc].u[3] = hi ? t1 : t0;
    }
#pragma unroll
    for (int dt = 0; dt < 4; ++dt) {
      oacc[dt] = __builtin_amdgcn_mfma_f32_16x16x32_bf16(vf0[dt], pf[0].v, oacc[dt], 0, 0, 0);
      oacc[dt] = __builtin_amdgcn_mfma_f32_16x16x32_bf16(vf1[dt], pf[1].v, oacc[dt], 0, 0, 0);
    }
  }

  float inv = 1.0f / l;
#pragma unroll
  for (int dt = 0; dt < 4; ++dt)
#pragma unroll
    for (int r = 0; r < 4; ++r)
      Os[w][l15 * 72 + dt * 16 + l4 * 4 + r] = f2b(oacc[dt][r] * inv);
  if (qrow < NTOK) {
    uint4 a  = *(const uint4*)&Os[w][l15 * 72 + l4 * 16];
    uint4 bq = *(const uint4*)&Os[w][l15 * 72 + l4 * 16 + 8];
    unsigned short* op = O + ((size_t)(b * NTOK + qrow)) * HID + head * 64;
    *(uint4*)(op + l4 * 16) = a;
    *(uint4*)(op + l4 * 16 + 8) = bq;
  }
}

// ---------------- host launch ----------------
extern "C" void kernel_launch(void* const* d_in, const int* in_sizes, int n_in,
                              void* d_out, int out_size, void* d_ws, size_t ws_size,
                              hipStream_t stream) {
  (void)in_sizes; (void)n_in; (void)out_size; (void)ws_size;
  const float* pv      = (const float*)d_in[0];
  const float* patch_w = (const float*)d_in[1];
  const float* patch_b = (const float*)d_in[2];
  const float* ln1_g   = (const float*)d_in[3];
  const float* ln1_b   = (const float*)d_in[4];
  const float* qw = (const float*)d_in[5];
  const float* qb = (const float*)d_in[6];
  const float* kw = (const float*)d_in[7];
  const float* kb = (const float*)d_in[8];
  const float* vw = (const float*)d_in[9];
  const float* vb = (const float*)d_in[10];
  const float* pw = (const float*)d_in[11];
  const float* pb = (const float*)d_in[12];
  const float* ln2_g = (const float*)d_in[13];
  const float* ln2_b = (const float*)d_in[14];
  const float* fc1w = (const float*)d_in[15];
  const float* fc1b = (const float*)d_in[16];
  const float* fc2w = (const float*)d_in[17];
  const float* fc2b = (const float*)d_in[18];
  const float* lnf_g = (const float*)d_in[19];
  const float* lnf_b = (const float*)d_in[20];

  char* wsp = (char*)d_ws;
  auto alloc = [&](size_t bytes) {
    char* p = wsp;
    wsp += (bytes + 255) & ~(size_t)255;
    return p;
  };
  unsigned short* wPatch = (unsigned short*)alloc((size_t)1024 * 1536 * 2);
  unsigned short* wQKV   = (unsigned short*)alloc((size_t)NLAYER * 3072 * 1024 * 2);
  unsigned short* wP     = (unsigned short*)alloc((size_t)NLAYER * HID * HID * 2);
  unsigned short* wF1    = (unsigned short*)alloc((size_t)NLAYER * MLPD * HID * 2);
  unsigned short* wF2    = (unsigned short*)alloc((size_t)NLAYER * HID * MLPD * 2);
  float*          qkvbias = (float*)alloc((size_t)NLAYER * 3072 * 4);
  unsigned short* Aim  = (unsigned short*)alloc((size_t)ROWS * CONVK * 2);
  float*          h    = (float*)alloc((size_t)ROWS * HID * 4);
  unsigned short* xnb  = (unsigned short*)alloc((size_t)ROWS * HID * 2);
  unsigned short* qkvo = (unsigned short*)alloc((size_t)ROWS * 3072 * 2);
  unsigned short* Qh   = (unsigned short*)alloc((size_t)ROWS * HID * 2 + 8192);
  unsigned short* Kh   = (unsigned short*)alloc((size_t)ROWS * HID * 2 + 8192);
  unsigned short* VT   = (unsigned short*)alloc((size_t)ROWS * HID * 2 + 8192);
  unsigned short* ob   = (unsigned short*)alloc((size_t)ROWS * HID * 2);
  unsigned short* mb   = (unsigned short*)alloc((size_t)ROWS * MLPD * 2);
  // split-K bf16 partials alias the Qh+Kh+VT region (~58MB, dead at every use site;
  // max need = fc1 z2: 2 x 25.7MB = 51.4MB). qkvprep rewrites Qh/Kh/VT after qkv-reduce.
  unsigned short* part = Qh;

  const int MN = ROWS * HID;            // 3.2M

  auto cast = [&](const float* s, unsigned short* d, long long n) {
    long long n4 = n / 4;
    int grid = (int)((n4 + 255) / 256);
    if (grid > 16384) grid = 16384;
    cast4_k<<<grid, 256, 0, stream>>>(s, d, n4);
  };
  cast(patch_w, wPatch, (long long)1024 * 1536);
  castqkv_k<<<dim3(4096, 3), 256, 0, stream>>>(qw, kw, vw, wQKV);
  cast(pw, wP, (long long)NLAYER * HID * HID);
  cast(fc1w, wF1, (long long)NLAYER * MLPD * HID);
  cast(fc2w, wF2, (long long)NLAYER * HID * MLPD);
  biascat_k<<<48, 256, 0, stream>>>(qb, kb, vb, qkvbias);

  im2col_k<<<(ROWS * CONVK) / 256, 256, 0, stream>>>(pv, Aim);
  // conv as GEMM, split-K x3 (600 blocks) -> h = sum + bias
  gemm_bt<<<dim3(8, 25, 3), 256, 0, stream>>>(Aim, wPatch, part, ROWS, HID, CONVK, 512);
  reduceN_k<3, 0, 0, 0><<<MN / 2048, 256, 0, stream>>>(
      part, patch_b, nullptr, h, nullptr, MN, HID);

  for (int i = 0; i < NLAYER; ++i) {
    ln_k<1><<<ROWS, 256, 0, stream>>>(h, ln1_g + i * HID, ln1_b + i * HID, xnb, nullptr);
    // qkv, split-K x2 (1200 blocks) -> qkvo bf16 (+bias)
    gemm_bt<<<dim3(24, 25, 2), 256, 0, stream>>>(
        xnb, wQKV + (size_t)i * 3072 * 1024, part, ROWS, 3072, HID, 512);
    reduceN_k<2, 0, 0, 1><<<(ROWS * 3072) / 2048, 256, 0, stream>>>(
        part, qkvbias + i * 3072, nullptr, nullptr, qkvo, ROWS * 3072, 3072);
    qkvprep_k<<<dim3(25, 32), 256, 0, stream>>>(qkvo, Qh, Kh, VT);
    flash4_k<<<dim3(32, 25), 256, 0, stream>>>(Qh, Kh, VT, ob);
    // proj, split-K x4 (800 blocks) -> h += proj(ob) + pb
    gemm_bt<<<dim3(8, 25, 4), 256, 0, stream>>>(
        ob, wP + (size_t)i * HID * HID, part, ROWS, HID, HID, 256);
    reduceN_k<4, 1, 0, 0><<<MN / 2048, 256, 0, stream>>>(
        part, pb + i * HID, h, h, nullptr, MN, HID);
    ln_k<1><<<ROWS, 256, 0, stream>>>(h, ln2_g + i * HID, ln2_b + i * HID, xnb, nullptr);
    // fc1, split-K x2 (1600 blocks) -> mb = gelu(sum + bias) bf16
    gemm_bt<<<dim3(32, 25, 2), 256, 0, stream>>>(
        xnb, wF1 + (size_t)i * MLPD * HID, part, ROWS, MLPD, HID, 512);
    reduceN_k<2, 0, 1, 1><<<(ROWS * MLPD) / 2048, 256, 0, stream>>>(
        part, fc1b + i * MLPD, nullptr, nullptr, mb, ROWS * MLPD, MLPD);
    // fc2, split-K x4 (800 blocks) -> h += fc2(mb) + fc2b
    gemm_bt<<<dim3(8, 25, 4), 256, 0, stream>>>(
        mb, wF2 + (size_t)i * HID * MLPD, part, ROWS, HID, MLPD, 1024);
    reduceN_k<4, 1, 0, 0><<<MN / 2048, 256, 0, stream>>>(
        part, fc2b + i * HID, h, h, nullptr, MN, HID);
  }
  ln_k<0><<<ROWS, 256, 0, stream>>>(h, lnf_g, lnf_b, nullptr, (float*)d_out);
}

// Round 7
// 1406.474 us; speedup vs baseline: 1.0703x; 1.0703x over previous
//
#include <hip/hip_runtime.h>
#include <math.h>

// ---------------- constants ----------------
#define NTOK   1568
#define BATCH  2
#define HID    1024
#define MLPD   4096
#define NLAYER 4
#define ROWS   (BATCH*NTOK)   // 3136
#define CONVK  1536

typedef __bf16 bf16x8 __attribute__((ext_vector_type(8)));
typedef float  f32x4  __attribute__((ext_vector_type(4)));

__device__ __forceinline__ unsigned short f2b(float f) {
  unsigned int u = __float_as_uint(f);
  unsigned int r = u + 0x7FFFu + ((u >> 16) & 1u);   // RNE
  return (unsigned short)(r >> 16);
}
__device__ __forceinline__ float b2f(unsigned short s) {
  return __uint_as_float((unsigned int)s << 16);
}

// async global->LDS 16B; lds ptr must be wave-uniform base (HW adds lane*16)
__device__ __forceinline__ void async16(const unsigned short* g, unsigned short* l) {
  __builtin_amdgcn_global_load_lds(
      (__attribute__((address_space(1))) void*)(void*)g,
      (__attribute__((address_space(3))) void*)(void*)l, 16, 0, 0);
}

// ---------------- fp32 -> bf16 cast (x4 vectorized, grid-stride) ----------------
__global__ __launch_bounds__(256) void cast4_k(const float* __restrict__ s,
                                               unsigned short* __restrict__ d,
                                               long long n4) {
  long long i = (long long)blockIdx.x * 256 + threadIdx.x;
  long long stride = (long long)gridDim.x * 256;
  for (; i < n4; i += stride) {
    float4 v = ((const float4*)s)[i];
    *(ushort4*)(d + i * 4) = make_ushort4(f2b(v.x), f2b(v.y), f2b(v.z), f2b(v.w));
  }
}

// cast q/k/v weights into one concatenated per-layer buffer wQKV[L][3072][1024]
__global__ __launch_bounds__(256) void castqkv_k(const float* __restrict__ q,
                                                 const float* __restrict__ k,
                                                 const float* __restrict__ v,
                                                 unsigned short* __restrict__ dst) {
  const float* src = blockIdx.y == 0 ? q : (blockIdx.y == 1 ? k : v);
  long long i4 = (long long)blockIdx.x * 256 + threadIdx.x;   // exactly L*HH/4
  long long e = i4 * 4;
  int layer = (int)(e >> 20);                                  // HH = 1<<20
  long long de = e + ((long long)(2 * layer + blockIdx.y) << 20);
  float4 val = ((const float4*)src)[i4];
  *(ushort4*)(dst + de) = make_ushort4(f2b(val.x), f2b(val.y), f2b(val.z), f2b(val.w));
}

__global__ __launch_bounds__(256) void biascat_k(const float* __restrict__ qb,
                                                 const float* __restrict__ kb,
                                                 const float* __restrict__ vb,
                                                 float* __restrict__ dst) {
  int idx = blockIdx.x * 256 + threadIdx.x;   // L*3072
  int layer = idx / 3072, c = idx % 3072;
  float v = c < 1024 ? qb[layer * 1024 + c]
            : (c < 2048 ? kb[layer * 1024 + c - 1024] : vb[layer * 1024 + c - 2048]);
  dst[idx] = v;
}

// ---------------- im2col for the tubelet conv ----------------
__global__ __launch_bounds__(256) void im2col_k(const float* __restrict__ pv,
                                                unsigned short* __restrict__ A) {
  int idx = blockIdx.x * 256 + threadIdx.x;       // exactly ROWS*CONVK threads
  int row = idx / CONVK, col = idx % CONVK;
  int b = row / NTOK, t = row % NTOK;
  int d = t / 196, r = t % 196, hh = r / 14, ww = r % 14;
  int c = col >> 9, r2 = col & 511, td = r2 >> 8, ph = (r2 >> 4) & 15, pw = r2 & 15;
  int frame = 2 * d + td;
  const float* src = pv + ((((long long)b * 16 + frame) * 3 + c) * 224 + (hh * 16 + ph)) * 224
                        + (ww * 16 + pw);
  A[idx] = f2b(*src);
}

// ---------------- GEMM: partial[z][M,N] = A[M,K_z](bf16) * B[N,K_z]^T(bf16) ----------
// Double-buffered LDS (1 barrier/iter, stage kt+1 then compute kt). blockIdx.z selects
// K-chunk; partial z written at outP + z*zStride (explicit stride for alias control).
__global__ __launch_bounds__(256) void gemm_bt(const unsigned short* __restrict__ A,
                                               const unsigned short* __restrict__ B,
                                               unsigned short* outP,
                                               int M, int N, int K, int kChunk,
                                               size_t zStride) {
  __shared__ unsigned short As[2][128 * 32];
  __shared__ unsigned short Bs[2][128 * 32];
  const int tid = threadIdx.x;
  const int lane = tid & 63;
  const int w = tid >> 6;
  const int wm = (w >> 1) * 64, wn = (w & 1) * 64;
  const int l15 = lane & 15, l4 = lane >> 4;
  const int bm = blockIdx.y, bn = blockIdx.x;
  const int wbase = tid & ~63;   // wave-uniform
  const int kbeg = blockIdx.z * kChunk;

  auto stage = [&](int buf, int k0) {
#pragma unroll
    for (int it = 0; it < 2; ++it) {
      int c = it * 256 + tid;
      int rowA = bm * 128 + (c >> 2);
      if (rowA >= M) rowA = M - 1;
      async16(A + (size_t)rowA * K + k0 + (c & 3) * 8, &As[buf][(it * 256 + wbase) * 8]);
      int rowB = bn * 128 + (c >> 2);
      async16(B + (size_t)rowB * K + k0 + (c & 3) * 8, &Bs[buf][(it * 256 + wbase) * 8]);
    }
  };

  f32x4 acc[4][4] = {};
  stage(0, kbeg);
  const int nIter = kChunk >> 5;

  for (int i = 0; i < nIter; ++i) {
    const int cur = i & 1;
    __syncthreads();               // drains stage(cur) issued one compute-phase ago
    if (i + 1 < nIter) stage(cur ^ 1, kbeg + (i + 1) * 32);

    bf16x8 af[4], bfr[4];
#pragma unroll
    for (int ii = 0; ii < 4; ++ii)
      af[ii] = *(const bf16x8*)&As[cur][(wm + ii * 16 + l15) * 32 + l4 * 8];
#pragma unroll
    for (int j = 0; j < 4; ++j)
      bfr[j] = *(const bf16x8*)&Bs[cur][(wn + j * 16 + l15) * 32 + l4 * 8];
#pragma unroll
    for (int ii = 0; ii < 4; ++ii)
#pragma unroll
      for (int j = 0; j < 4; ++j)
        acc[ii][j] = __builtin_amdgcn_mfma_f32_16x16x32_bf16(af[ii], bfr[j], acc[ii][j], 0, 0, 0);
  }

  unsigned short* pout = outP + (size_t)blockIdx.z * zStride;
#pragma unroll
  for (int ii = 0; ii < 4; ++ii) {
    int rowb = bm * 128 + wm + ii * 16 + l4 * 4;
#pragma unroll
    for (int r = 0; r < 4; ++r) {
      int rr = rowb + r;
      if (rr >= M) continue;
#pragma unroll
      for (int j = 0; j < 4; ++j) {
        int col = bn * 128 + wn + j * 16 + l15;
        pout[(size_t)rr * N + col] = f2b(acc[ii][j][r]);
      }
    }
  }
}

// ---------------- split-K reduce: sum NP bf16 partials + bias (+gelu) -> bf16 --------
// NOTE: no __restrict__ on p/outB — fc1 places partial z1 exactly at its output (mb),
// relying on same-thread read-before-write.
template <int NP, int GELU>
__global__ __launch_bounds__(256) void reduceN_k(const unsigned short* p,
                                                 const float* __restrict__ bias,
                                                 unsigned short* outB,
                                                 int MN, int N, size_t pStride) {
  int i8 = blockIdx.x * 256 + threadIdx.x;   // exactly MN/8 threads
  int e = i8 * 8;
  float acc[8];
#pragma unroll
  for (int j = 0; j < 8; ++j) acc[j] = 0.0f;
#pragma unroll
  for (int pp = 0; pp < NP; ++pp) {
    const unsigned short* src = p + (size_t)pp * pStride + e;
    ushort4 a0 = *(const ushort4*)src;
    ushort4 a1 = *(const ushort4*)(src + 4);
    acc[0] += b2f(a0.x); acc[1] += b2f(a0.y); acc[2] += b2f(a0.z); acc[3] += b2f(a0.w);
    acc[4] += b2f(a1.x); acc[5] += b2f(a1.y); acc[6] += b2f(a1.z); acc[7] += b2f(a1.w);
  }
  int col = e % N;                           // N % 8 == 0
  float4 b0 = *(const float4*)(bias + col);
  float4 b1 = *(const float4*)(bias + col + 4);
  acc[0] += b0.x; acc[1] += b0.y; acc[2] += b0.z; acc[3] += b0.w;
  acc[4] += b1.x; acc[5] += b1.y; acc[6] += b1.z; acc[7] += b1.w;
  if (GELU) {
#pragma unroll
    for (int j = 0; j < 8; ++j)
      acc[j] = 0.5f * acc[j] * (1.0f + erff(acc[j] * 0.70710678118654752f));
  }
  *(ushort4*)(outB + e) = make_ushort4(f2b(acc[0]), f2b(acc[1]), f2b(acc[2]), f2b(acc[3]));
  *(ushort4*)(outB + e + 4) = make_ushort4(f2b(acc[4]), f2b(acc[5]), f2b(acc[6]), f2b(acc[7]));
}

// ---------------- fused split-K reduce + residual + LayerNorm ------------------------
// One block per row (HID=1024, 4 cols/thread). Sums NP bf16 partials + bias (+resid),
// writes the fp32 residual stream (unless FINAL), then LayerNorms the row:
// FINAL=0 -> bf16 xnOut; FINAL=1 -> fp32 fOut (lnf -> d_out).
template <int NP, int RESID, int FINAL>
__global__ __launch_bounds__(256) void redln_k(const unsigned short* __restrict__ p,
                                               const float* __restrict__ bias,
                                               const float* resid,
                                               const float* __restrict__ g,
                                               const float* __restrict__ b,
                                               float* hOut,
                                               unsigned short* __restrict__ xnOut,
                                               float* __restrict__ fOut,
                                               size_t pStride) {
  __shared__ float red[8];
  const int row = blockIdx.x, tid = threadIdx.x;
  const int col = tid * 4;
  const size_t off = (size_t)row * HID + col;
  float v0 = 0, v1 = 0, v2 = 0, v3 = 0;
#pragma unroll
  for (int pp = 0; pp < NP; ++pp) {
    ushort4 a = *(const ushort4*)(p + (size_t)pp * pStride + off);
    v0 += b2f(a.x); v1 += b2f(a.y); v2 += b2f(a.z); v3 += b2f(a.w);
  }
  float4 bs = *(const float4*)(bias + col);
  v0 += bs.x; v1 += bs.y; v2 += bs.z; v3 += bs.w;
  if (RESID) {
    float4 r = *(const float4*)(resid + off);
    v0 += r.x; v1 += r.y; v2 += r.z; v3 += r.w;
  }
  if (!FINAL) *(float4*)(hOut + off) = make_float4(v0, v1, v2, v3);
  float s = v0 + v1 + v2 + v3;
  float q = v0 * v0 + v1 * v1 + v2 * v2 + v3 * v3;
  for (int o2 = 32; o2; o2 >>= 1) { s += __shfl_xor(s, o2); q += __shfl_xor(q, o2); }
  if ((tid & 63) == 0) { red[tid >> 6] = s; red[4 + (tid >> 6)] = q; }
  __syncthreads();
  float ts = red[0] + red[1] + red[2] + red[3];
  float tq = red[4] + red[5] + red[6] + red[7];
  float mu = ts * (1.0f / HID);
  float var = tq * (1.0f / HID) - mu * mu;
  float rs = rsqrtf(var + 1e-6f);
  float o0 = (v0 - mu) * rs * g[col + 0] + b[col + 0];
  float o1 = (v1 - mu) * rs * g[col + 1] + b[col + 1];
  float o2 = (v2 - mu) * rs * g[col + 2] + b[col + 2];
  float o3 = (v3 - mu) * rs * g[col + 3] + b[col + 3];
  if (FINAL) {
    *(float4*)(fOut + off) = make_float4(o0, o1, o2, o3);
  } else {
    *(ushort4*)(xnOut + off) = make_ushort4(f2b(o0), f2b(o1), f2b(o2), f2b(o3));
  }
}

// ---------------- QKV prep: RoPE(q,k)+scale -> head-major; V -> per-head transposed ----
// grid (25 token-tiles, 32 bh); block 256
__global__ __launch_bounds__(256) void qkvprep_k(const unsigned short* __restrict__ qkvb,
                                                 unsigned short* __restrict__ Qh,
                                                 unsigned short* __restrict__ Kh,
                                                 unsigned short* __restrict__ VT) {
  __shared__ unsigned short Vs[64 * 72];
  const int tile = blockIdx.x, bh = blockIdx.y;
  const int b = bh >> 4, head = bh & 15;
  const int tid = threadIdx.x;
  const int tl = tid >> 2, dc = tid & 3;
  const int tg = tile * 64 + tl;
  const int trc = tg < NTOK ? tg : NTOK - 1;
  const bool valid = tg < NTOK;
  const size_t srow = ((size_t)(b * NTOK + trc)) * 3072 + head * 64 + dc * 16;

  // V chunk -> LDS
  {
    uint4 v0 = *(const uint4*)(qkvb + srow + 2048);
    uint4 v1 = *(const uint4*)(qkvb + srow + 2048 + 8);
    *(uint4*)&Vs[tl * 72 + dc * 16] = v0;
    *(uint4*)&Vs[tl * 72 + dc * 16 + 8] = v1;
  }

  // RoPE on q,k (8 pairs per thread)
  const int t = trc;
  const int dpos = t / 196, rem = t - dpos * 196, hpos = rem / 14, wpos = rem - hpos * 14;
  const float LG = 0.9210340371976184f;  // ln(10000)/10
  union V16 { uint4 u[2]; unsigned short s[16]; };
  V16 qin, kin, qout, kout;
  qin.u[0] = *(const uint4*)(qkvb + srow);
  qin.u[1] = *(const uint4*)(qkvb + srow + 8);
  kin.u[0] = *(const uint4*)(qkvb + srow + 1024);
  kin.u[1] = *(const uint4*)(qkvb + srow + 1024 + 8);
#pragma unroll
  for (int p = 0; p < 8; ++p) {
    int d0 = dc * 16 + 2 * p;
    float qx0 = b2f(qin.s[2 * p]), qx1 = b2f(qin.s[2 * p + 1]);
    float kx0 = b2f(kin.s[2 * p]), kx1 = b2f(kin.s[2 * p + 1]);
    float qo0, qo1, ko0, ko1;
    if (d0 >= 60) { qo0 = qx0; qo1 = qx1; ko0 = kx0; ko1 = kx1; }
    else {
      int region = d0 / 20;
      int j0 = d0 - region * 20;
      int pos = region == 0 ? dpos : (region == 1 ? hpos : wpos);
      float fp = (float)pos;
      int i0 = j0 % 10, i1 = (j0 + 1) % 10;
      float f0 = expf(-LG * (float)i0) * fp;
      float f1 = expf(-LG * (float)i1) * fp;
      float c0 = cosf(f0), s0 = sinf(f0), c1 = cosf(f1), s1 = sinf(f1);
      qo0 = qx0 * c0 - qx1 * s0; qo1 = qx1 * c1 + qx0 * s1;
      ko0 = kx0 * c0 - kx1 * s0; ko1 = kx1 * c1 + kx0 * s1;
    }
    qout.s[2 * p]     = f2b(qo0 * 0.125f);     // fold attention scale into Q
    qout.s[2 * p + 1] = f2b(qo1 * 0.125f);
    kout.s[2 * p]     = f2b(ko0);
    kout.s[2 * p + 1] = f2b(ko1);
  }
  if (valid) {
    size_t drow = ((size_t)bh * NTOK + tg) * 64 + dc * 16;
    *(uint4*)(Qh + drow)     = qout.u[0];
    *(uint4*)(Qh + drow + 8) = qout.u[1];
    *(uint4*)(Kh + drow)     = kout.u[0];
    *(uint4*)(Kh + drow + 8) = kout.u[1];
  }
  __syncthreads();
  // V transpose out: thread = (dim, token-chunk)
  {
    int d = tid >> 2, tc = tid & 3;
    if (tile * 64 + tc * 16 < NTOK) {
      V16 o;
#pragma unroll
      for (int jj = 0; jj < 16; ++jj) o.s[jj] = Vs[(tc * 16 + jj) * 72 + d];
      unsigned short* dst = VT + ((size_t)bh * 64 + d) * NTOK + tile * 64 + tc * 16;
      *(uint4*)dst = o.u[0];
      *(uint4*)(dst + 8) = o.u[1];
    }
  }
}

// ---------------- flash attention v5: KV-split x2, async LDS dbuf, partials ----------
// grid (32 bh, 25 q-tiles, 2 kv). Each block walks its K-tile range, emits
// unnormalized O~ (bf16) + (m,l) fp32 partials. Os aliased into Ks (LDS=32KB -> 4 blk/CU).
__global__ __launch_bounds__(256, 4) void flash5_k(const unsigned short* __restrict__ Qh,
                                                   const unsigned short* __restrict__ Kh,
                                                   const unsigned short* __restrict__ VT,
                                                   unsigned short* __restrict__ Opart,
                                                   float2* __restrict__ ml) {
  __shared__ unsigned short Ks[2][64 * 64];
  __shared__ unsigned short Vs[2][64 * 64];
  const int bh = blockIdx.x, qt = blockIdx.y, kv = blockIdx.z;
  const int kt0 = kv ? 13 : 0, kt1 = kv ? 25 : 13;
  const int tid = threadIdx.x, lane = tid & 63, w = tid >> 6;
  const int l15 = lane & 15, l4 = lane >> 4;
  const size_t hb = (size_t)bh * NTOK * 64;
  const unsigned short* kgp = Kh + hb;
  const unsigned short* vbp = VT + (size_t)bh * 64 * NTOK;

  const int srow0 = w * 8 + (lane >> 3);          // it=0 row
  const int scg0  = (lane & 7) ^ (srow0 & 7);
  const int srow1 = srow0 + 32;                   // it=1 row
  const int scg1  = (lane & 7) ^ (srow1 & 7);

  const int qrow = qt * 64 + w * 16 + l15;
  const int qrc = qrow < NTOK ? qrow : NTOK - 1;
  bf16x8 q0 = *(const bf16x8*)(Qh + hb + (size_t)qrc * 64 + l4 * 8);
  bf16x8 q1 = *(const bf16x8*)(Qh + hb + (size_t)qrc * 64 + 32 + l4 * 8);

  f32x4 oacc[4] = {};
  float m = -1e30f, l = 0.0f;

  {  // prologue: stage first tile into buffer 0
    const int kc0 = kt0 * 64;
    async16(kgp + (size_t)(kc0 + srow0) * 64 + scg0 * 8, &Ks[0][(size_t)w * 512]);
    async16(kgp + (size_t)(kc0 + srow1) * 64 + scg1 * 8, &Ks[0][(size_t)(w + 4) * 512]);
    async16(vbp + (size_t)srow0 * NTOK + kc0 + scg0 * 8, &Vs[0][(size_t)w * 512]);
    async16(vbp + (size_t)srow1 * NTOK + kc0 + scg1 * 8, &Vs[0][(size_t)(w + 4) * 512]);
  }

  const int h7 = l15 & 7;
  const int p1 = (l4 ^ h7) * 8;          // phys offset of logical chunk l4
  const int p2 = ((l4 + 4) ^ h7) * 8;    // phys offset of logical chunk l4+4

  for (int kt = kt0; kt < kt1; ++kt) {
    const int cur = (kt - kt0) & 1, nxt = cur ^ 1;
    const int kb = kt * 64;
    __syncthreads();   // vmcnt(0) drain: prefetch from last iter guaranteed landed

    if (kt + 1 < kt1) {
      const int kn = kb + 64;
      async16(kgp + (size_t)(kn + srow0) * 64 + scg0 * 8, &Ks[nxt][(size_t)w * 512]);
      async16(kgp + (size_t)(kn + srow1) * 64 + scg1 * 8, &Ks[nxt][(size_t)(w + 4) * 512]);
      async16(vbp + (size_t)srow0 * NTOK + kn + scg0 * 8, &Vs[nxt][(size_t)w * 512]);
      async16(vbp + (size_t)srow1 * NTOK + kn + scg1 * 8, &Vs[nxt][(size_t)(w + 4) * 512]);
    }

    bf16x8 kc0[4], kc1[4];
#pragma unroll
    for (int nt = 0; nt < 4; ++nt) {
      const unsigned short* kr = &Ks[cur][(nt * 16 + l15) * 64];
      kc0[nt] = *(const bf16x8*)(kr + p1);
      kc1[nt] = *(const bf16x8*)(kr + p2);
    }
    f32x4 s[4] = {};
#pragma unroll
    for (int nt = 0; nt < 4; ++nt) {
      s[nt] = __builtin_amdgcn_mfma_f32_16x16x32_bf16(kc0[nt], q0, s[nt], 0, 0, 0);
      s[nt] = __builtin_amdgcn_mfma_f32_16x16x32_bf16(kc1[nt], q1, s[nt], 0, 0, 0);
    }
    bf16x8 vf0[4], vf1[4];
#pragma unroll
    for (int dt = 0; dt < 4; ++dt) {
      const unsigned short* vr = &Vs[cur][(dt * 16 + l15) * 64];
      vf0[dt] = *(const bf16x8*)(vr + p1);
      vf1[dt] = *(const bf16x8*)(vr + p2);
    }

    if (kb + 64 > NTOK) {
#pragma unroll
      for (int nt = 0; nt < 4; ++nt)
#pragma unroll
        for (int r = 0; r < 4; ++r)
          if (kb + nt * 16 + l4 * 4 + r >= NTOK) s[nt][r] = -1e30f;
    }
    float rmax = s[0][0];
#pragma unroll
    for (int nt = 0; nt < 4; ++nt)
#pragma unroll
      for (int r = 0; r < 4; ++r) rmax = fmaxf(rmax, s[nt][r]);
    rmax = fmaxf(rmax, __shfl_xor(rmax, 16));
    rmax = fmaxf(rmax, __shfl_xor(rmax, 32));
    float mn = fmaxf(m, rmax);
    float alpha = __expf(m - mn);
    m = mn;
    float rsum = 0.0f;
#pragma unroll
    for (int nt = 0; nt < 4; ++nt)
#pragma unroll
      for (int r = 0; r < 4; ++r) {
        float p = __expf(s[nt][r] - mn);
        s[nt][r] = p;
        rsum += p;
      }
    rsum += __shfl_xor(rsum, 16);
    rsum += __shfl_xor(rsum, 32);
    l = l * alpha + rsum;
#pragma unroll
    for (int dt = 0; dt < 4; ++dt)
#pragma unroll
      for (int r = 0; r < 4; ++r) oacc[dt][r] *= alpha;

    unsigned pk01[4], pk23[4];
#pragma unroll
    for (int nt = 0; nt < 4; ++nt) {
      pk01[nt] = (unsigned)f2b(s[nt][0]) | ((unsigned)f2b(s[nt][1]) << 16);
      pk23[nt] = (unsigned)f2b(s[nt][2]) | ((unsigned)f2b(s[nt][3]) << 16);
    }
    const int srcA = ((l4 & 1) << 5) | l15;
    const int srcB = srcA + 16;
    const bool hi = (l4 >> 1) != 0;
    union PB { unsigned u[4]; bf16x8 v; } pf[2];
#pragma unroll
    for (int kc = 0; kc < 2; ++kc) {
      unsigned t0, t1;
      t0 = __shfl(pk01[2 * kc], srcA); t1 = __shfl(pk01[2 * kc + 1], srcA);
      pf[kc].u[0] = hi ? t1 : t0;
      t0 = __shfl(pk23[2 * kc], srcA); t1 = __shfl(pk23[2 * kc + 1], srcA);
      pf[kc].u[1] = hi ? t1 : t0;
      t0 = __shfl(pk01[2 * kc], srcB); t1 = __shfl(pk01[2 * kc + 1], srcB);
      pf[kc].u[2] = hi ? t1 : t0;
      t0 = __shfl(pk23[2 * kc], srcB); t1 = __shfl(pk23[2 * kc + 1], srcB);
      pf[kc].u[3] = hi ? t1 : t0;
    }
#pragma unroll
    for (int dt = 0; dt < 4; ++dt) {
      oacc[dt] = __builtin_amdgcn_mfma_f32_16x16x32_bf16(vf0[dt], pf[0].v, oacc[dt], 0, 0, 0);
      oacc[dt] = __builtin_amdgcn_mfma_f32_16x16x32_bf16(vf1[dt], pf[1].v, oacc[dt], 0, 0, 0);
    }
  }

  // epilogue: O~^T -> LDS transpose (aliased into Ks after barrier) -> bf16 partial
  __syncthreads();                          // all waves done reading Ks/Vs
  unsigned short* Os = &Ks[0][0];           // 4*1152 ushorts fit in Ks (8192)
#pragma unroll
  for (int dt = 0; dt < 4; ++dt)
#pragma unroll
    for (int r = 0; r < 4; ++r)
      Os[w * 1152 + l15 * 72 + dt * 16 + l4 * 4 + r] = f2b(oacc[dt][r]);
  if (qrow < NTOK) {
    uint4 a  = *(const uint4*)&Os[w * 1152 + l15 * 72 + l4 * 16];
    uint4 bq = *(const uint4*)&Os[w * 1152 + l15 * 72 + l4 * 16 + 8];
    unsigned short* op = Opart + ((size_t)(kv * 32 + bh) * NTOK + qrow) * 64;
    *(uint4*)(op + l4 * 16) = a;
    *(uint4*)(op + l4 * 16 + 8) = bq;
    if (l4 == 0) ml[(size_t)(kv * 32 + bh) * NTOK + qrow] = make_float2(m, l);
  }
}

// ---------------- combine the two KV-split partials -> ob ----------------------------
__global__ __launch_bounds__(256) void fcomb_k(const unsigned short* __restrict__ Op,
                                               const float2* __restrict__ ml,
                                               unsigned short* __restrict__ O) {
  const int bh = blockIdx.x, qt = blockIdx.y;
  const int tid = threadIdx.x;
  const int qr = qt * 64 + (tid >> 2);
  const int dc = (tid & 3) * 16;
  if (qr >= NTOK) return;
  const int b = bh >> 4, head = bh & 15;
  float2 a0 = ml[(size_t)bh * NTOK + qr];          // kv=0: (m, l)
  float2 a1 = ml[(size_t)(32 + bh) * NTOK + qr];   // kv=1
  float M = fmaxf(a0.x, a1.x);
  float w0 = __expf(a0.x - M), w1 = __expf(a1.x - M);
  float inv = 1.0f / (a0.y * w0 + a1.y * w1);
  w0 *= inv; w1 *= inv;
  union V16 { uint4 u[2]; unsigned short s[16]; } p0, p1, o;
  const unsigned short* q0 = Op + ((size_t)bh * NTOK + qr) * 64 + dc;
  const unsigned short* q1 = Op + ((size_t)(32 + bh) * NTOK + qr) * 64 + dc;
  p0.u[0] = *(const uint4*)q0;       p0.u[1] = *(const uint4*)(q0 + 8);
  p1.u[0] = *(const uint4*)q1;       p1.u[1] = *(const uint4*)(q1 + 8);
#pragma unroll
  for (int j = 0; j < 16; ++j) o.s[j] = f2b(b2f(p0.s[j]) * w0 + b2f(p1.s[j]) * w1);
  unsigned short* dst = O + ((size_t)(b * NTOK + qr)) * HID + head * 64 + dc;
  *(uint4*)dst = o.u[0];
  *(uint4*)(dst + 8) = o.u[1];
}

// ---------------- host launch ----------------
extern "C" void kernel_launch(void* const* d_in, const int* in_sizes, int n_in,
                              void* d_out, int out_size, void* d_ws, size_t ws_size,
                              hipStream_t stream) {
  (void)in_sizes; (void)n_in; (void)out_size; (void)ws_size;
  const float* pv      = (const float*)d_in[0];
  const float* patch_w = (const float*)d_in[1];
  const float* patch_b = (const float*)d_in[2];
  const float* ln1_g   = (const float*)d_in[3];
  const float* ln1_b   = (const float*)d_in[4];
  const float* qw = (const float*)d_in[5];
  const float* qb = (const float*)d_in[6];
  const float* kw = (const float*)d_in[7];
  const float* kb = (const float*)d_in[8];
  const float* vw = (const float*)d_in[9];
  const float* vb = (const float*)d_in[10];
  const float* pw = (const float*)d_in[11];
  const float* pb = (const float*)d_in[12];
  const float* ln2_g = (const float*)d_in[13];
  const float* ln2_b = (const float*)d_in[14];
  const float* fc1w = (const float*)d_in[15];
  const float* fc1b = (const float*)d_in[16];
  const float* fc2w = (const float*)d_in[17];
  const float* fc2b = (const float*)d_in[18];
  const float* lnf_g = (const float*)d_in[19];
  const float* lnf_b = (const float*)d_in[20];

  char* wsp = (char*)d_ws;
  auto alloc = [&](size_t bytes) {
    char* p = wsp;
    wsp += (bytes + 255) & ~(size_t)255;
    return p;
  };
  unsigned short* wPatch = (unsigned short*)alloc((size_t)1024 * 1536 * 2);
  unsigned short* wQKV   = (unsigned short*)alloc((size_t)NLAYER * 3072 * 1024 * 2);
  unsigned short* wP     = (unsigned short*)alloc((size_t)NLAYER * HID * HID * 2);
  unsigned short* wF1    = (unsigned short*)alloc((size_t)NLAYER * MLPD * HID * 2);
  unsigned short* wF2    = (unsigned short*)alloc((size_t)NLAYER * HID * MLPD * 2);
  float*          qkvbias = (float*)alloc((size_t)NLAYER * 3072 * 4);
  unsigned short* Aim  = (unsigned short*)alloc((size_t)ROWS * CONVK * 2);
  float*          h    = (float*)alloc((size_t)ROWS * HID * 4);
  unsigned short* xnb  = (unsigned short*)alloc((size_t)ROWS * HID * 2);
  unsigned short* qkvo = (unsigned short*)alloc((size_t)ROWS * 3072 * 2);
  unsigned short* Qh   = (unsigned short*)alloc((size_t)ROWS * HID * 2 + 8192);
  unsigned short* Kh   = (unsigned short*)alloc((size_t)ROWS * HID * 2 + 8192);
  unsigned short* VT   = (unsigned short*)alloc((size_t)ROWS * HID * 2 + 8192);
  unsigned short* ob   = (unsigned short*)alloc((size_t)ROWS * HID * 2);
  unsigned short* mb   = (unsigned short*)alloc((size_t)ROWS * MLPD * 2);

  // Aliasing plan (all stream-ordered; every aliased producer finishes before consumer):
  //  part  (=Qh): conv z3 (19.3MB), qkv z2 (38.5MB, spans dead ob+Opart), fc1 z0,
  //               fc2 z4 (25.69MB, spans dead ob) -- never touches each gemm's A.
  //  partM (=mb): proj z4 (25.7MB; ob is proj's A, so proj partials must NOT hit ob).
  //  fc1 z1 placed EXACTLY at mb (reduce thread reads its own address before writing).
  //  Opart/ml (=mb): flash partials, consumed by fcomb before proj overwrites mb.
  unsigned short* part  = Qh;
  unsigned short* partM = mb;
  unsigned short* Opart = mb;
  float2*         mlbuf = (float2*)(mb + (size_t)2 * 32 * NTOK * 64);
  const size_t MNs = (size_t)ROWS * HID;
  const size_t strideF1 = (size_t)(mb - part);   // ushort elems from Qh to mb

  auto cast = [&](const float* s, unsigned short* d, long long n) {
    long long n4 = n / 4;
    int grid = (int)((n4 + 255) / 256);
    if (grid > 16384) grid = 16384;
    cast4_k<<<grid, 256, 0, stream>>>(s, d, n4);
  };
  cast(patch_w, wPatch, (long long)1024 * 1536);
  castqkv_k<<<dim3(4096, 3), 256, 0, stream>>>(qw, kw, vw, wQKV);
  cast(pw, wP, (long long)NLAYER * HID * HID);
  cast(fc1w, wF1, (long long)NLAYER * MLPD * HID);
  cast(fc2w, wF2, (long long)NLAYER * HID * MLPD);
  biascat_k<<<48, 256, 0, stream>>>(qb, kb, vb, qkvbias);

  im2col_k<<<(ROWS * CONVK) / 256, 256, 0, stream>>>(pv, Aim);
  // conv GEMM split-K x3 -> h = sum+bias, xnb = LN1_0(h)
  gemm_bt<<<dim3(8, 25, 3), 256, 0, stream>>>(Aim, wPatch, part, ROWS, HID, CONVK, 512, MNs);
  redln_k<3, 0, 0><<<ROWS, 256, 0, stream>>>(
      part, patch_b, nullptr, ln1_g, ln1_b, h, xnb, nullptr, MNs);

  for (int i = 0; i < NLAYER; ++i) {
    // qkv split-K x2 -> qkvo bf16
    gemm_bt<<<dim3(24, 25, 2), 256, 0, stream>>>(
        xnb, wQKV + (size_t)i * 3072 * 1024, part, ROWS, 3072, HID, 512,
        (size_t)ROWS * 3072);
    reduceN_k<2, 0><<<(ROWS * 3072) / 2048, 256, 0, stream>>>(
        part, qkvbias + i * 3072, qkvo, ROWS * 3072, 3072, (size_t)ROWS * 3072);
    qkvprep_k<<<dim3(25, 32), 256, 0, stream>>>(qkvo, Qh, Kh, VT);
    flash5_k<<<dim3(32, 25, 2), 256, 0, stream>>>(Qh, Kh, VT, Opart, mlbuf);
    fcomb_k<<<dim3(32, 25), 256, 0, stream>>>(Opart, mlbuf, ob);
    // proj split-K x4 (partials in mb, NOT ob) -> h += proj+pb, xnb = LN2(h)
    gemm_bt<<<dim3(8, 25, 4), 256, 0, stream>>>(
        ob, wP + (size_t)i * HID * HID, partM, ROWS, HID, HID, 256, MNs);
    redln_k<4, 1, 0><<<ROWS, 256, 0, stream>>>(
        partM, pb + i * HID, h, ln2_g + i * HID, ln2_b + i * HID, h, xnb, nullptr, MNs);
    // fc1 split-K x2 (z0 at Qh-span, z1 exactly at mb) -> mb = gelu(sum+bias)
    gemm_bt<<<dim3(32, 25, 2), 256, 0, stream>>>(
        xnb, wF1 + (size_t)i * MLPD * HID, part, ROWS, MLPD, HID, 512, strideF1);
    reduceN_k<2, 1><<<(ROWS * MLPD) / 2048, 256, 0, stream>>>(
        part, fc1b + i * MLPD, mb, ROWS * MLPD, MLPD, strideF1);
    // fc2 split-K x4 -> h += fc2+bias, then LN1(next) or LNf->out
    gemm_bt<<<dim3(8, 25, 4), 256, 0, stream>>>(
        mb, wF2 + (size_t)i * HID * MLPD, part, ROWS, HID, MLPD, 1024, MNs);
    if (i < NLAYER - 1) {
      redln_k<4, 1, 0><<<ROWS, 256, 0, stream>>>(
          part, fc2b + i * HID, h, ln1_g + (i + 1) * HID, ln1_b + (i + 1) * HID,
          h, xnb, nullptr, MNs);
    } else {
      redln_k<4, 1, 1><<<ROWS, 256, 0, stream>>>(
          part, fc2b + i * HID, h, lnf_g, lnf_b, nullptr, nullptr, (float*)d_out, MNs);
    }
  }
}